// Round 5
// baseline (47478.534 us; speedup 1.0000x reference)
//
#include <hip/hip_runtime.h>
#include <math.h>

#define NSYMB  40000
#define NMODES 256
#define LEAD   20000

// glibc hypotf algorithm: exact double sum, sqrt, single round to f32 (CR)
static __device__ __forceinline__ float crhypotf(float a, float b) {
    const double da = (double)a, db = (double)b;
    return (float)sqrt(da * da + db * db);
}

// 256 independent sequential PLL chains, one lane per mode.
// Bit-faithful mirror of an f32 numpy translation of the reference JAXPR,
// including the reverse-mode AD chain of jax.grad(Lk):
//   forward: e=(cos,sin) [CR f32], z=y*e (numpy complex-mul order, no FMA)
//   backward: ct_z=(2wre,-2wim) exact (abs-transpose: fl(2r)/r == 2.0 exact),
//             ct_e=mul(ct_z,y), ct_v=mul(ct_e,e), gk=-Im(ct_v)
// Momentum filter telescopes exactly (u0_t == g_t, even for f32 and ±0),
// so phi_{t+1} = fl(phi - fl(Kv*gk)). unwrap(period=pi/2) all-f32 inline.
__global__ __launch_bounds__(64)
void ddpll_seq(const float* __restrict__ ei_re,
               const float* __restrict__ ei_im,
               const float* __restrict__ tx_re,
               const float* __restrict__ tx_im,
               const float* __restrict__ eta,
               float* __restrict__ out)
{
#pragma clang fp contract(off)   // numpy/XLA-CPU do not fuse mul+add
    const int m = blockIdx.x * 64 + threadIdx.x;   // mode 0..255
    const float Kv = (float)tanh((double)eta[0]);  // CR f32 tanh

    // constellation exactly as numpy: f64 level/sqrt(10) -> f32
    const double s10 = sqrt(10.0);
    float Lre[16], Lim[16];
    {
        float Lf[4];
        Lf[0] = (float)(-3.0 / s10); Lf[1] = (float)(-1.0 / s10);
        Lf[2] = (float)( 1.0 / s10); Lf[3] = (float)( 3.0 / s10);
        for (int k = 0; k < 16; ++k) { Lre[k] = Lf[k >> 2]; Lim[k] = Lf[k & 3]; }
    }

    const float P2f = 1.57079632679489661923f;   // f32(pi/2)
    const float P4f = 0.78539816339744830961f;   // f32(pi/4)

    float phi = 0.0f, prev = 0.0f, cum = 0.0f;   // all-f32 scan state + unwrap
    float* __restrict__ theta_out = out + (size_t)2 * NSYMB * NMODES;

    for (int t = 0; t < NSYMB; ++t) {
        const int idx = t * NMODES + m;
        const float yre = ei_re[idx];
        const float yim = ei_im[idx];

        // ---- unwrap bookkeeping on pre-update phase (numpy f32 semantics) ----
        const float th = phi;
        if (t > 0) {
            const float dd = th - prev;             // np.diff (f32)
            if (!(fabsf(dd) < P4f)) {               // correction unless < discont
                float x  = dd + P4f;
                float rm = fmodf(x, P2f);           // exact IEEE remainder
                if (rm < 0.0f) rm += P2f;           // numpy floor-mod (y>0)
                float ddmod = rm - P4f;             // in [-pi/4, pi/4)
                if (ddmod == -P4f && dd > 0.0f) ddmod = P4f;  // boundary rule
                cum += (ddmod - dd);                // sequential f32 cumsum
            }
        }
        prev = th;
        theta_out[idx] = th + cum;                  // unwrapped theta (f32)

        // ---- forward: e = (cos,sin) CR f32; z = y*e (numpy c64 mul) ----
        double sd, cd;
        sincos((double)phi, &sd, &cd);              // f64 -> round = CR f32
        const float c = (float)cd, s = (float)sd;
        const float zre = (yre * c) - (yim * s);
        const float zim = (yre * s) + (yim * c);

        // ---- reverse-mode AD chain: ct_z = (A, B) ----
        float A, B;
        if (t < LEAD) {                             // pilot branch (m=0)
            const float wre = zre - tx_re[idx];
            const float wim = zim - tx_im[idx];
            A = 2.0f * wre;                         // exact
            B = -(2.0f * wim);                      // exact
        } else {                                    // decision branch (m=1)
            float dv[16], rv[16], wres[16], wims[16];
            float dmin = __builtin_inff();
            for (int k = 0; k < 16; ++k) {
                const float wre = zre - Lre[k];
                const float wim = zim - Lim[k];
                const float r = crhypotf(wre, wim); // = glibc hypotf bits
                const float d = r * r;              // integer_pow(r,2)
                wres[k] = wre; wims[k] = wim; rv[k] = r; dv[k] = d;
                dmin = fminf(dmin, d);              // reduce_min (exact)
            }
            int cnt = 0;
            for (int k = 0; k < 16; ++k) cnt += (dv[k] == dmin) ? 1 : 0;
            if (cnt == 1) {                         // unique argmin: exact path
                int j = 0;
                for (int k = 0; k < 16; ++k) if (dv[k] == dmin) j = k;
                A = 2.0f * wres[j];
                B = -(2.0f * wims[j]);
            } else {                                // jax chooser tie-average
                const float ctd = 1.0f / (float)cnt;
                float sa = 0.0f, sb = 0.0f;
                for (int k = 0; k < 16; ++k) {
                    if (dv[k] == dmin) {
                        const float ctr  = (2.0f * rv[k]) * ctd;
                        const float ctm2 = ctr / rv[k];
                        sa += (ctm2 * wres[k]);
                        sb += -(ctm2 * wims[k]);
                    }
                }
                A = sa; B = sb;
            }
        }
        // ct_e = mul(ct_z, y); ct_v = mul(ct_e, e); gk = -Im(ct_v)
        const float ct_e_re = (A * yre) - (B * yim);
        const float ct_e_im = (A * yim) + (B * yre);
        const float ct_v_im = (ct_e_re * s) + (ct_e_im * c);
        const float gk = -ct_v_im;

        phi = phi - (Kv * gk);                      // scan carry update
    }
}

// Parallel epilogue: Eo = Ei * exp(i * theta_unwrapped)  (errors ~1e-6 << thr)
__global__ __launch_bounds__(256)
void ddpll_rot(const float* __restrict__ ei_re,
               const float* __restrict__ ei_im,
               float* __restrict__ out)
{
    const int idx = blockIdx.x * 256 + threadIdx.x;
    const float U = out[(size_t)2 * NSYMB * NMODES + idx];
    float su, cu;
    sincosf(U, &su, &cu);
    const float yre = ei_re[idx], yim = ei_im[idx];
    out[2 * idx]     = (yre * cu) - (yim * su);
    out[2 * idx + 1] = (yre * su) + (yim * cu);
}

extern "C" void kernel_launch(void* const* d_in, const int* in_sizes, int n_in,
                              void* d_out, int out_size, void* d_ws, size_t ws_size,
                              hipStream_t stream)
{
    (void)in_sizes; (void)n_in; (void)out_size; (void)d_ws; (void)ws_size;
    const float* ei_re = (const float*)d_in[0];
    const float* ei_im = (const float*)d_in[1];
    ddpll_seq<<<dim3(NMODES / 64), dim3(64), 0, stream>>>(
        ei_re, ei_im,
        (const float*)d_in[2],
        (const float*)d_in[3],
        (const float*)d_in[4],
        (float*)d_out);
    ddpll_rot<<<dim3(NSYMB * NMODES / 256), dim3(256), 0, stream>>>(
        ei_re, ei_im, (float*)d_out);
}

// Round 6
// 16198.149 us; speedup vs baseline: 2.9311x; 2.9311x over previous
//
#include <hip/hip_runtime.h>
#include <math.h>

#define NSYMB  40000
#define NMODES 256
#define LEAD   20000
#define UF     8      // prefetch depth: 8*~150cyc compute > ~900cyc HBM latency

// glibc hypotf equivalent: exact double sum, sqrt, single round to f32 (CR)
static __device__ __forceinline__ float crhypotf(float a, float b) {
    const double da = (double)a, db = (double)b;
    return (float)sqrt(da * da + db * db);
}

// Correctly-rounded f32 sincos via bounded-range f64 eval (fdlibm-style).
// |x| < 1e6 always here (phi random-walks to ~1e2); 33-bit Cody-Waite pio2_1
// keeps fma(-fn,pio2_1,x) exact; total err <= ~0.6 ulp f64 -> same f32 bits
// as any CR implementation except ~4e-9/call boundary cases.
static __device__ __forceinline__ void cr_sincosf(double x, float& sf, float& cf) {
    if (fabs(x) > 1.0e6) {  // bit-safety fallback, never expected
        double sd, cd; sincos(x, &sd, &cd); sf = (float)sd; cf = (float)cd; return;
    }
    const double invpio2 = 6.36619772367581382433e-01;
    const double pio2_1  = 1.57079632673412561417e+00;   // 33 bits of pi/2
    const double pio2_1t = 6.07710050650619224932e-11;   // pi/2 - pio2_1
    double fn = __builtin_rint(x * invpio2);
    double r  = __builtin_fma(-fn, pio2_1, x);           // exact
    double y  = r - fn * pio2_1t;
    double z  = y * y;
    double ps = __builtin_fma(z, 1.58969099521155010221e-10, -2.50507602534068634195e-08);
    ps = __builtin_fma(z, ps,  2.75573137070700676789e-06);
    ps = __builtin_fma(z, ps, -1.98412698298579493134e-04);
    ps = __builtin_fma(z, ps,  8.33333333332248946124e-03);
    ps = __builtin_fma(z, ps, -1.66666666666666324348e-01);
    double sv = __builtin_fma(y * z, ps, y);
    double pc = __builtin_fma(z, -1.13596475577881948265e-11, 2.08757232129817482790e-09);
    pc = __builtin_fma(z, pc, -2.75573143513906633035e-07);
    pc = __builtin_fma(z, pc,  2.48015872894767294178e-05);
    pc = __builtin_fma(z, pc, -1.38888888888741095749e-03);
    pc = __builtin_fma(z, pc,  4.16666666666666019037e-02);
    double hz = 0.5 * z;
    double w1 = 1.0 - hz;
    double cv = w1 + (((1.0 - w1) - hz) + z * (z * pc)); // fdlibm careful form
    const int n = ((int)fn) & 3;
    const float S = (float)sv, C = (float)cv;
    if      (n == 0) { sf = S;  cf = C;  }
    else if (n == 1) { sf = C;  cf = -S; }
    else if (n == 2) { sf = -S; cf = -C; }
    else             { sf = -C; cf = S;  }
}

// One PLL step — bit-identical to the R5 (passing) trajectory.
// PILOT=true: pilot target; false: decision-directed with margin-band gate
// (outside 1e-4 of any decision bisector, separable quantize == CR-hypot
// argmin provably, and ties are impossible; inside the band run the
// numpy-literal 16-point argmin + jax tie-average verbatim).
template<bool PILOT>
static __device__ __forceinline__ void pll_step(
    int t, int idx, float yre, float yim, float txr, float txi,
    float Kv, const float* Lf,
    float& phi, float& prev, float& cum, float* __restrict__ theta_out,
    float* __restrict__ out)
{
#pragma clang fp contract(off)
    const float P2f  = 1.57079632679489661923f;  // f32(pi/2)
    const float P4f  = 0.78539816339744830961f;  // f32(pi/4)
    const float QTHf = 0.63245553203367588f;     // bisector 2/sqrt(10)

    // ---- unwrap bookkeeping on pre-update phase (off the phi-chain) ----
    const float th = phi;
    if (t > 0) {
        const float dd = th - prev;
        if (!(fabsf(dd) < P4f)) {
            float xx = dd + P4f;
            float rm = fmodf(xx, P2f);
            if (rm < 0.0f) rm += P2f;               // numpy floor-mod
            float ddmod = rm - P4f;
            if (ddmod == -P4f && dd > 0.0f) ddmod = P4f;
            cum += (ddmod - dd);
        }
    }
    prev = th;
    theta_out[idx] = th + cum;

    // ---- forward: e=(cos,sin) CR f32; z = y*e (numpy c64 mul, no FMA) ----
    float s, c;
    cr_sincosf((double)phi, s, c);
    const float zre = (yre * c) - (yim * s);
    const float zim = (yre * s) + (yim * c);

    // ---- reverse-mode AD chain: ct_z = (A, B) ----
    float A, B;
    if (PILOT) {
        const float wre = zre - txr;
        const float wim = zim - txi;
        A = 2.0f * wre;
        B = -(2.0f * wim);
    } else {
        const float ar = fabsf(zre), ai = fabsf(zim);
        const float mr = fminf(fabsf(ar - QTHf), ar);
        const float mi = fminf(fabsf(ai - QTHf), ai);
        if (mr > 1e-4f && mi > 1e-4f) {
            // fast path: selection == numpy argmin (provable), A/B bits equal
            const float tr = (zre < 0.0f) ? ((zre < -QTHf) ? Lf[0] : Lf[1])
                                          : ((zre <  QTHf) ? Lf[2] : Lf[3]);
            const float ti = (zim < 0.0f) ? ((zim < -QTHf) ? Lf[0] : Lf[1])
                                          : ((zim <  QTHf) ? Lf[2] : Lf[3]);
            const float wre = zre - tr;
            const float wim = zim - ti;
            A = 2.0f * wre;
            B = -(2.0f * wim);
        } else {
            // numpy-literal path (R5 verbatim)
            float dv[16], rv[16], wres[16], wims[16];
            float dmin = __builtin_inff();
            for (int k = 0; k < 16; ++k) {
                const float wre = zre - Lf[k >> 2];
                const float wim = zim - Lf[k & 3];
                const float r = crhypotf(wre, wim);
                const float d = r * r;
                wres[k] = wre; wims[k] = wim; rv[k] = r; dv[k] = d;
                dmin = fminf(dmin, d);
            }
            int cnt = 0;
            for (int k = 0; k < 16; ++k) cnt += (dv[k] == dmin) ? 1 : 0;
            if (cnt == 1) {
                int j = 0;
                for (int k = 0; k < 16; ++k) if (dv[k] == dmin) j = k;
                A = 2.0f * wres[j];
                B = -(2.0f * wims[j]);
            } else {
                const float ctd = 1.0f / (float)cnt;
                float sa = 0.0f, sb = 0.0f;
                for (int k = 0; k < 16; ++k) {
                    if (dv[k] == dmin) {
                        const float ctr  = (2.0f * rv[k]) * ctd;
                        const float ctm2 = ctr / rv[k];
                        sa += (ctm2 * wres[k]);
                        sb += -(ctm2 * wims[k]);
                    }
                }
                A = sa; B = sb;
            }
        }
    }
    // ct_e = mul(ct_z, y); ct_v = mul(ct_e, e); gk = -Im(ct_v)
    const float ct_e_re = (A * yre) - (B * yim);
    const float ct_e_im = (A * yim) + (B * yre);
    const float ct_v_im = (ct_e_re * s) + (ct_e_im * c);
    const float gk = -ct_v_im;
    phi = phi - (Kv * gk);
    (void)out;
}

__global__ __launch_bounds__(64)
void ddpll_seq(const float* __restrict__ ei_re,
               const float* __restrict__ ei_im,
               const float* __restrict__ tx_re,
               const float* __restrict__ tx_im,
               const float* __restrict__ eta,
               float* __restrict__ out)
{
#pragma clang fp contract(off)
    const int m = blockIdx.x * 64 + threadIdx.x;   // mode 0..255
    const float Kv = (float)tanh((double)eta[0]);  // CR f32 tanh

    const double s10 = sqrt(10.0);
    float Lf[4];
    Lf[0] = (float)(-3.0 / s10); Lf[1] = (float)(-1.0 / s10);
    Lf[2] = (float)( 1.0 / s10); Lf[3] = (float)( 3.0 / s10);

    float phi = 0.0f, prev = 0.0f, cum = 0.0f;
    float* __restrict__ theta_out = out + (size_t)2 * NSYMB * NMODES;

    // ================= phase 1: pilot (t < LEAD) =================
    float pyr[UF], pyi[UF], pxr[UF], pxi[UF];
#pragma unroll
    for (int j = 0; j < UF; ++j) {
        const int idx = j * NMODES + m;
        pyr[j] = ei_re[idx]; pyi[j] = ei_im[idx];
        pxr[j] = tx_re[idx]; pxi[j] = tx_im[idx];
    }
    for (int tb = 0; tb < LEAD; tb += UF) {
        float yr[UF], yi[UF], xr[UF], xi[UF];
#pragma unroll
        for (int j = 0; j < UF; ++j) { yr[j]=pyr[j]; yi[j]=pyi[j]; xr[j]=pxr[j]; xi[j]=pxi[j]; }
        const int nb = tb + UF;
        if (nb < LEAD) {
#pragma unroll
            for (int j = 0; j < UF; ++j) {           // prefetch next block
                const int idx = (nb + j) * NMODES + m;
                pyr[j] = ei_re[idx]; pyi[j] = ei_im[idx];
                pxr[j] = tx_re[idx]; pxi[j] = tx_im[idx];
            }
        }
#pragma unroll
        for (int j = 0; j < UF; ++j)
            pll_step<true>(tb + j, (tb + j) * NMODES + m, yr[j], yi[j], xr[j], xi[j],
                           Kv, Lf, phi, prev, cum, theta_out, out);
    }

    // ================= phase 2: decision-directed =================
#pragma unroll
    for (int j = 0; j < UF; ++j) {
        const int idx = (LEAD + j) * NMODES + m;
        pyr[j] = ei_re[idx]; pyi[j] = ei_im[idx];
    }
    for (int tb = LEAD; tb < NSYMB; tb += UF) {
        float yr[UF], yi[UF];
#pragma unroll
        for (int j = 0; j < UF; ++j) { yr[j]=pyr[j]; yi[j]=pyi[j]; }
        const int nb = tb + UF;
        if (nb < NSYMB) {
#pragma unroll
            for (int j = 0; j < UF; ++j) {           // prefetch next block
                const int idx = (nb + j) * NMODES + m;
                pyr[j] = ei_re[idx]; pyi[j] = ei_im[idx];
            }
        }
#pragma unroll
        for (int j = 0; j < UF; ++j)
            pll_step<false>(tb + j, (tb + j) * NMODES + m, yr[j], yi[j], 0.0f, 0.0f,
                            Kv, Lf, phi, prev, cum, theta_out, out);
    }
}

// Parallel epilogue: Eo = Ei * exp(i * theta_unwrapped)  (err ~1e-6 << thr)
__global__ __launch_bounds__(256)
void ddpll_rot(const float* __restrict__ ei_re,
               const float* __restrict__ ei_im,
               float* __restrict__ out)
{
    const int idx = blockIdx.x * 256 + threadIdx.x;
    const float U = out[(size_t)2 * NSYMB * NMODES + idx];
    float su, cu;
    sincosf(U, &su, &cu);
    const float yre = ei_re[idx], yim = ei_im[idx];
    out[2 * idx]     = (yre * cu) - (yim * su);
    out[2 * idx + 1] = (yre * su) + (yim * cu);
}

extern "C" void kernel_launch(void* const* d_in, const int* in_sizes, int n_in,
                              void* d_out, int out_size, void* d_ws, size_t ws_size,
                              hipStream_t stream)
{
    (void)in_sizes; (void)n_in; (void)out_size; (void)d_ws; (void)ws_size;
    const float* ei_re = (const float*)d_in[0];
    const float* ei_im = (const float*)d_in[1];
    ddpll_seq<<<dim3(NMODES / 64), dim3(64), 0, stream>>>(
        ei_re, ei_im,
        (const float*)d_in[2],
        (const float*)d_in[3],
        (const float*)d_in[4],
        (float*)d_out);
    ddpll_rot<<<dim3(NSYMB * NMODES / 256), dim3(256), 0, stream>>>(
        ei_re, ei_im, (float*)d_out);
}